// Round 1
// 624.894 us; speedup vs baseline: 1.0541x; 1.0541x over previous
//
#include <hip/hip_runtime.h>
#include <stdint.h>

typedef unsigned short u16;
typedef u16 u16x8 __attribute__((ext_vector_type(8)));
typedef __bf16 bf16x8 __attribute__((ext_vector_type(8)));
typedef float f32x4 __attribute__((ext_vector_type(4)));

__device__ __forceinline__ float b2f(u16 u) {
    union { unsigned int i; float f; } c; c.i = ((unsigned int)u) << 16; return c.f;
}
__device__ __forceinline__ u16 f2b(float f) {  // round-to-nearest-even
    unsigned int u = __float_as_uint(f);
    u += 0x7fff + ((u >> 16) & 1);
    return (u16)(u >> 16);
}

// async global->LDS, 16B per lane. LDS dest is wave-uniform base + lane*16
// (lane0's pointer IS the wave base in our tid-linear layout).
typedef const __attribute__((address_space(1))) unsigned int* gas_p;
typedef __attribute__((address_space(3))) unsigned int* las_p;
__device__ __forceinline__ void gll16(const void* g, void* l) {
    __builtin_amdgcn_global_load_lds((gas_p)g, (las_p)l, 16, 0, 0);
}

// ---------------------------------------------------------------------------
// dtype detector. mask is exactly {0.0,1.0}. If stored f32, every even u16
// (little-endian low half) is 0x0000. If stored bf16, even u16s are the even
// ELEMENTS: ~50% are 0x3F80. flag: 0 = f32, 1 = bf16.
// ---------------------------------------------------------------------------
__global__ __launch_bounds__(1024) void detect_dtype(const u16* __restrict__ m,
                                                     int* __restrict__ flag) {
    __shared__ int s;
    int t = threadIdx.x;
    if (t == 0) s = 0;
    __syncthreads();
    if (m[2 * t] != 0) atomicOr(&s, 1);
    __syncthreads();
    if (t == 0) *flag = s;
}

// ---------------------------------------------------------------------------
// Canonicalize bias/ENet params to f32 scratch (concatenated, 11345 floats):
// b1[0,512) b2[512,1024) b3[1024,11024) E1w[11024,+16) E1b[11040,+16)
// E2w[11056,+256) E2b[11312,+16) E3w[11328,+16) E3b[11344]
// Runtime dtype branch (single dispatch).
// ---------------------------------------------------------------------------
__global__ __launch_bounds__(256) void canon_params(
        const void* b1, const void* b2, const void* b3,
        const void* E1w, const void* E1b, const void* E2w,
        const void* E2b, const void* E3w, const void* E3b,
        const int* __restrict__ flag, float* __restrict__ dst) {
    const int DT = *flag;
    int i = blockIdx.x * 256 + threadIdx.x;
    if (i >= 11345) return;
    const void* srcs[9] = {b1, b2, b3, E1w, E1b, E2w, E2b, E3w, E3b};
    const int off[10] = {0, 512, 1024, 11024, 11040, 11056, 11312, 11328, 11344, 11345};
    int s = 0;
    while (i >= off[s + 1]) ++s;
    int j = i - off[s];
    dst[i] = (DT == 1) ? b2f(((const u16*)srcs[s])[j]) : ((const float*)srcs[s])[j];
}

// ---------------------------------------------------------------------------
// Transpose with zero-pad: out[c][r] = (r<R && c<C) ? in[r][c] : 0, r in [0,ldo)
// Runtime input dtype from flag (0 f32, 1 bf16); output always bf16.
// ---------------------------------------------------------------------------
__global__ __launch_bounds__(256) void transpose_pad(const void* __restrict__ vin,
        u16* __restrict__ out, const int* __restrict__ flag,
        int R, int C, int ldi, int ldo) {
    const int DT = *flag;
    __shared__ __align__(16) u16 tile[64][72];
    const int rt = blockIdx.x * 64;
    const int ct = blockIdx.y * 64;
    const int t = threadIdx.x;
    const int lr = t >> 2;
    const int lc = (t & 3) * 16;
    const int r = rt + lr;
    if (r < R && (ct + lc + 15) < C) {
        if (DT == 1) {
            const u16* p = (const u16*)vin + (long)r * ldi + ct + lc;
            *(u16x8*)&tile[lr][lc]     = *(const u16x8*)p;
            *(u16x8*)&tile[lr][lc + 8] = *(const u16x8*)(p + 8);
        } else {
            const float* p = (const float*)vin + (long)r * ldi + ct + lc;
            #pragma unroll
            for (int q = 0; q < 4; ++q) {
                f32x4 v4 = *(const f32x4*)(p + q * 4);
                #pragma unroll
                for (int j = 0; j < 4; ++j) tile[lr][lc + q * 4 + j] = f2b(v4[j]);
            }
        }
    } else {
        #pragma unroll
        for (int j = 0; j < 16; ++j) {
            int c = ct + lc + j;
            u16 v = 0;
            if (r < R && c < C)
                v = (DT == 1) ? ((const u16*)vin)[(long)r * ldi + c]
                              : f2b(((const float*)vin)[(long)r * ldi + c]);
            tile[lr][lc + j] = v;
        }
    }
    __syncthreads();
    const int oc = ct + lr;
    if (oc >= C) return;
    u16x8 w0, w1;
    #pragma unroll
    for (int j = 0; j < 8; ++j) w0[j] = tile[lc + j][lr];
    #pragma unroll
    for (int j = 0; j < 8; ++j) w1[j] = tile[lc + 8 + j][lr];
    long ob = (long)oc * ldo + rt + lc;
    if (rt + lc + 15 < ldo) {
        *(u16x8*)(out + ob)     = w0;
        *(u16x8*)(out + ob + 8) = w1;
    } else {
        #pragma unroll
        for (int j = 0; j < 16; ++j) {
            int orr = rt + lc + j;
            if (orr < ldo) out[(long)oc * ldo + orr] = (j < 8) ? w0[j] : w1[j - 8];
        }
    }
}

// ---------------------------------------------------------------------------
// ENet LUT from canonical f32 params: lut[i] = e(-16 + i/128), i in [0,4096).
// ---------------------------------------------------------------------------
__global__ __launch_bounds__(256) void build_elut(const float* __restrict__ P,
                                                  float* __restrict__ lut) {
    const float* E1w = P + 11024; const float* E1b = P + 11040;
    const float* E2w = P + 11056; const float* E2b = P + 11312;
    const float* E3w = P + 11328; const float* E3b = P + 11344;
    int i = blockIdx.x * 256 + threadIdx.x;
    if (i >= 4096) return;
    float v = -16.f + (float)i * (1.f / 128.f);
    float e1[16];
    #pragma unroll
    for (int j = 0; j < 16; ++j) e1[j] = tanhf(v * E1w[j] + E1b[j]);
    float e = E3b[0];
    #pragma unroll
    for (int k = 0; k < 16; ++k) {
        float s = E2b[k];
        #pragma unroll
        for (int j = 0; j < 16; ++j) s += e1[j] * E2w[j * 16 + k];
        e += tanhf(s) * E3w[k];
    }
    lut[i] = e;
}

// ---------------------------------------------------------------------------
// bf16 GEMM: C[M,N] = A[M,K] * Bt[N,K]^T. 128x128 tile, BK=32, 4 waves.
// XDT: dtype of external arrays — MODE 2: A (=x); MODE 1: mask & out.
// MODE 0: h2 = tanh(acc+bias) (all-internal, ungated: pass flag=nullptr)
// MODE 1: fused ENet-LUT + 0.8v residual + mask select
// MODE 2: split-K raw fp32 partials
//
// Staging: when A is bf16 (all modes except MODE2/XDT=0), full K-steps use
// global_load_lds width-16 (m97 structure: one vmcnt drain per step, no VGPR
// round-trip). The K-tail (K%32!=0, GEMM1 only) and the f32-x variant fall
// back to predicated register staging.
// LDS layout XOR-swizzle: the 16B k-block at (row, j) holds global k-block
// j ^ (row&3). gll writes stay linear (dest = base + lane*16); the swizzle
// is applied to the per-lane GLOBAL source address (m173 pattern) and to the
// ds_read address. Drops fragment-read bank conflicts 8-way -> 4-way.
// ---------------------------------------------------------------------------
template<int MODE, int XDT>
__global__ __launch_bounds__(256, 4) void gemm_bt(
        const void* __restrict__ A, const u16* __restrict__ Bt,
        const float* __restrict__ biasf, void* __restrict__ Cb,
        float* __restrict__ Cf, const void* __restrict__ mask,
        const float* __restrict__ lut, const int* __restrict__ flag,
        int M, int N, int K, int Kloop, int kchunk, int ldA, int ldB, int ldC) {
    if (flag && *flag != XDT) return;
    constexpr int ADT = (MODE == 2) ? XDT : 1;   // h1/h2 are always bf16
    constexpr bool GLL = (ADT == 1);

    __shared__ __align__(16) u16 Alds[128 * 32];
    __shared__ __align__(16) u16 Blds[128 * 32];
    __shared__ __align__(16) float lutS[(MODE == 1) ? 4096 : 4];

    const int tid = threadIdx.x;
    const int m0 = blockIdx.x * 128;
    const int n0 = blockIdx.y * 128;
    const int lane = tid & 63;
    const int w = tid >> 6;
    const int wm = (w >> 1) * 64;
    const int wn = (w & 1) * 64;
    const int lm = lane & 15;
    const int lq = lane >> 4;

    if (MODE == 1) {
        const f32x4* s = (const f32x4*)lut;
        f32x4* d = (f32x4*)lutS;
        #pragma unroll
        for (int i = 0; i < 4; ++i) d[tid + 256 * i] = s[tid + 256 * i];
    }

    const int arow = tid >> 2;
    // XOR-swizzled source k-block: this lane's LDS slot (linear, tid*16B)
    // holds global k-block (tid&3)^(row&3).
    const int kq8 = (((tid & 3) ^ (arow & 3))) * 8;
    const long aoff = (long)(m0 + arow) * ldA + kq8;
    const long boff = (long)(n0 + arow) * ldB + kq8;
    u16* aldst0 = &Alds[tid * 8];
    u16* aldst1 = &Alds[tid * 8 + 2048];
    u16* bldst0 = &Blds[tid * 8];
    u16* bldst1 = &Blds[tid * 8 + 2048];
    const bool bv0 = (n0 + arow) < N;
    const bool bv1 = (n0 + arow + 64) < N;

    // fragment reads: logical k-block lq of row (wm|wn)+lm lives at
    // swizzled block lq ^ (row&3); row&3 == lm&3 since wm/wn are mult of 64.
    const int sx = (lq ^ (lm & 3)) * 8;
    const u16* aB = &Alds[(wm + lm) * 32 + sx];
    const u16* bB = &Blds[(wn + lm) * 32 + sx];

    const f32x4 zero = {0.f, 0.f, 0.f, 0.f};
    const u16x8 z8 = {0, 0, 0, 0, 0, 0, 0, 0};
    f32x4 acc[4][4];
    #pragma unroll
    for (int i = 0; i < 4; ++i)
        #pragma unroll
        for (int j = 0; j < 4; ++j) acc[i][j] = zero;

    int kb = 0, ke = Kloop;
    if (MODE == 2) { kb = blockIdx.z * kchunk; ke = min(Kloop, kb + kchunk); }

    const u16* Au16 = (const u16*)A;

    for (int k0 = kb; k0 < ke; k0 += 32) {
        if (GLL && (k0 + 32 <= K)) {
            // m97 structure: barrier (protect prev ds_reads), issue 4x gll,
            // barrier (drains vmcnt -> tile resident).
            // B rows beyond N (MODE1 edge block) read in-bounds garbage from
            // the adjacent ws region; it only pollutes acc lanes whose
            // col >= N, which the epilogue skips.
            __syncthreads();
            gll16(Au16 + aoff + k0, aldst0);
            gll16(Au16 + aoff + 64 * (long)ldA + k0, aldst1);
            gll16(Bt + boff + k0, bldst0);
            gll16(Bt + boff + 64 * (long)ldB + k0, bldst1);
            __syncthreads();
        } else {
            const bool av = (k0 + kq8) < K;   // K%8==0: 8-slot all-valid or not
            u16x8 ra0 = z8, ra1 = z8;
            if (ADT == 1) {
                if (av) {
                    ra0 = *(const u16x8*)(Au16 + aoff + k0);
                    ra1 = *(const u16x8*)(Au16 + aoff + 64 * (long)ldA + k0);
                }
            } else {
                const float* Af = (const float*)A;
                if (av) {
                    f32x4 l0 = *(const f32x4*)(Af + aoff + k0);
                    f32x4 h0 = *(const f32x4*)(Af + aoff + k0 + 4);
                    f32x4 l1 = *(const f32x4*)(Af + aoff + 64 * (long)ldA + k0);
                    f32x4 h1 = *(const f32x4*)(Af + aoff + 64 * (long)ldA + k0 + 4);
                    #pragma unroll
                    for (int j = 0; j < 4; ++j) {
                        ra0[j] = f2b(l0[j]); ra0[4 + j] = f2b(h0[j]);
                        ra1[j] = f2b(l1[j]); ra1[4 + j] = f2b(h1[j]);
                    }
                }
            }
            u16x8 rb0 = bv0 ? *(const u16x8*)(Bt + boff + k0) : z8;
            u16x8 rb1 = bv1 ? *(const u16x8*)(Bt + boff + 64 * (long)ldB + k0) : z8;
            __syncthreads();
            *(u16x8*)aldst0 = ra0;
            *(u16x8*)aldst1 = ra1;
            *(u16x8*)bldst0 = rb0;
            *(u16x8*)bldst1 = rb1;
            __syncthreads();
        }
        bf16x8 a[4], b[4];
        #pragma unroll
        for (int i = 0; i < 4; ++i) a[i] = *(const bf16x8*)(aB + i * 512);
        #pragma unroll
        for (int i = 0; i < 4; ++i) b[i] = *(const bf16x8*)(bB + i * 512);
        #pragma unroll
        for (int mi = 0; mi < 4; ++mi)
            #pragma unroll
            for (int ni = 0; ni < 4; ++ni)
                acc[mi][ni] = __builtin_amdgcn_mfma_f32_16x16x32_bf16(
                    a[mi], b[ni], acc[mi][ni], 0, 0, 0);
    }

    // epilogue. C/D layout: col = lane&15, row = (lane>>4)*4 + r  [m89/m91]
    if (MODE == 2) {
        float* dst = Cf + (long)blockIdx.z * M * (long)N;
        #pragma unroll
        for (int mi = 0; mi < 4; ++mi) {
            const int row0 = m0 + wm + mi * 16 + lq * 4;
            #pragma unroll
            for (int ni = 0; ni < 4; ++ni) {
                const int col = n0 + wn + ni * 16 + lm;
                #pragma unroll
                for (int r = 0; r < 4; ++r)
                    dst[(long)(row0 + r) * ldC + col] = acc[mi][ni][r];
            }
        }
    } else if (MODE == 0) {
        #pragma unroll
        for (int mi = 0; mi < 4; ++mi) {
            const int row0 = m0 + wm + mi * 16 + lq * 4;
            #pragma unroll
            for (int ni = 0; ni < 4; ++ni) {
                const int col = n0 + wn + ni * 16 + lm;
                const float bc = biasf[col];
                #pragma unroll
                for (int r = 0; r < 4; ++r) {
                    float v = acc[mi][ni][r] + bc;
                    ((u16*)Cb)[(long)(row0 + r) * ldC + col] = f2b(tanhf(v));
                }
            }
        }
    } else {
        #pragma unroll
        for (int mi = 0; mi < 4; ++mi) {
            const int row0 = m0 + wm + mi * 16 + lq * 4;
            #pragma unroll
            for (int ni = 0; ni < 4; ++ni) {
                const int col = n0 + wn + ni * 16 + lm;
                if (col < N) {
                    const float bc = biasf[col];
                    #pragma unroll
                    for (int r = 0; r < 4; ++r) {
                        float v = acc[mi][ni][r] + bc;
                        float fi = (v + 16.f) * 128.f + 0.5f;
                        int idx = (int)fi;
                        idx = idx < 0 ? 0 : (idx > 4095 ? 4095 : idx);
                        float y = lutS[idx] + 0.8f * v;
                        long off = (long)(row0 + r) * ldC + col;
                        float mk = (XDT == 1) ? b2f(((const u16*)mask)[off])
                                              : ((const float*)mask)[off];
                        float res = mk > 0.f ? y : v;
                        if (XDT == 1) ((u16*)Cb)[off] = f2b(res);
                        else          ((float*)Cb)[off] = res;
                    }
                }
            }
        }
    }
}

// reduce 8 split-K fp32 partials + f32 bias, tanh -> bf16 h1. col = i & 511.
__global__ __launch_bounds__(256) void reduce_tanh8(const float* __restrict__ p,
        const float* __restrict__ biasf, u16* __restrict__ h, int MN) {
    int i = (blockIdx.x * 256 + threadIdx.x) * 4;
    if (i >= MN) return;
    f32x4 s = *(const f32x4*)(p + i);
    #pragma unroll
    for (int z = 1; z < 8; ++z) s += *(const f32x4*)(p + (long)z * MN + i);
    int col = i & 511;
    #pragma unroll
    for (int c = 0; c < 4; ++c)
        h[i + c] = f2b(tanhf(s[c] + biasf[col + c]));
}

extern "C" void kernel_launch(void* const* d_in, const int* in_sizes, int n_in,
                              void* d_out, int out_size, void* d_ws, size_t ws_size,
                              hipStream_t stream) {
    const void* x    = d_in[0];
    const void* mask = d_in[1];
    const void* W1   = d_in[2];
    const void* b1   = d_in[3];
    const void* W2   = d_in[4];
    const void* b2   = d_in[5];
    const void* W3   = d_in[6];
    const void* b3   = d_in[7];

    const int B = 4096, D = 10000, H = 512, KP = 10016;

    // d_out as scratch (all dead before gemm3's full overwrite; min(d_out) =
    // 81.92 MB >= 81.56 MB used):
    // W1T [0, 10,256,384) ; partial(8 slices) [10,256,384, 77,365,248) ;
    // h1 [77,365,248, 81,559,552). W2T aliases the partial region (dead after
    // reduce_tanh8; its transpose is launched after the reduce).
    char* ob = (char*)d_out;
    u16*   W1T     = (u16*)ob;                   // 512*10016*2    = 10,256,384
    float* partial = (float*)(ob + 10256384);    // 8*4096*512*4   = 67,108,864
    u16*   h1      = (u16*)(ob + 77365248);      // 4096*512*2     =  4,194,304
    u16*   W2T     = (u16*)(ob + 10256384);      // 512*512*2 (aliases partial)

    // d_ws: live during gemm3 + control data. 14.50 MB total.
    char* ws = (char*)d_ws;
    u16*   W3T   = (u16*)ws;                    // 10,240,000
    u16*   h2    = (u16*)(ws + 10240000);       //  4,194,304
    float* elut  = (float*)(ws + 14434304);     //     16,384
    int*   flag  = (int*)(ws + 14450688);       //         16
    float* canon = (float*)(ws + 14450704);     // 11,345*4 = 45,380
    float* b1f = canon, * b2f = canon + 512, * b3f = canon + 1024;

    detect_dtype<<<1, 1024, 0, stream>>>((const u16*)mask, flag);

    canon_params<<<45, 256, 0, stream>>>(b1, b2, b3, d_in[8], d_in[9],
        d_in[10], d_in[11], d_in[12], d_in[13], flag, canon);

    transpose_pad<<<dim3(157, 8), 256, 0, stream>>>(W1, W1T, flag, D, H, H, KP);
    transpose_pad<<<dim3(8, 157), 256, 0, stream>>>(W3, W3T, flag, H, D, D, H);

    build_elut<<<16, 256, 0, stream>>>(canon, elut);

    // GEMM1 split-K=8: partial = x @ W1T^T (both dtype variants, self-gated)
    // kchunk=1280 (mult of 32); z=7 chunk covers [8960,10016) incl. K-tail.
    gemm_bt<2, 0><<<dim3(32, 4, 8), 256, 0, stream>>>(x, W1T, nullptr, nullptr,
        partial, nullptr, nullptr, flag, B, H, D, KP, 1280, D, KP, H);
    gemm_bt<2, 1><<<dim3(32, 4, 8), 256, 0, stream>>>(x, W1T, nullptr, nullptr,
        partial, nullptr, nullptr, flag, B, H, D, KP, 1280, D, KP, H);
    reduce_tanh8<<<(B * H) / 1024, 256, 0, stream>>>(partial, b1f, h1, B * H);

    // W2 transpose into the now-dead partial region
    transpose_pad<<<dim3(8, 8), 256, 0, stream>>>(W2, W2T, flag, H, H, H, H);

    // GEMM2 (all-internal, ungated)
    gemm_bt<0, 1><<<dim3(32, 4), 256, 0, stream>>>(h1, W2T, b2f, h2, nullptr,
        nullptr, nullptr, nullptr, B, H, H, H, 0, H, H, H);

    // GEMM3 + fused ENet/mask epilogue -> out (both dtype variants, self-gated)
    gemm_bt<1, 0><<<dim3(32, 79), 256, 0, stream>>>(h2, W3T, b3f, d_out, nullptr,
        mask, elut, flag, B, D, H, H, 0, H, H, D);
    gemm_bt<1, 1><<<dim3(32, 79), 256, 0, stream>>>(h2, W3T, b3f, d_out, nullptr,
        mask, elut, flag, B, D, H, H, 0, H, H, D);
}